// Round 1
// 290.205 us; speedup vs baseline: 1.0219x; 1.0219x over previous
//
#include <hip/hip_runtime.h>
#include <stdint.h>

#define B_ 4
#define T_ 2048
#define C_ 1024
#define H_ 16
#define HD_ 64

typedef __attribute__((ext_vector_type(8))) short short8;
typedef __attribute__((ext_vector_type(4))) float f32x4;

typedef uint32_t __attribute__((address_space(3))) lds_u32;
typedef const uint32_t __attribute__((address_space(1))) glb_u32;

__device__ inline void async16(const void* g, void* l) {
    __builtin_amdgcn_global_load_lds((glb_u32*)g, (lds_u32*)l, 16, 0, 0);
}

__device__ inline short f2bf(float f) {
    union { float f; uint32_t u; } x; x.f = f;
    uint32_t r = (x.u + 0x7fffu + ((x.u >> 16) & 1u)) >> 16;
    return (short)r;
}
__device__ inline float bf2f(short b) {
    union { uint32_t u; float f; } x; x.u = ((uint32_t)(uint16_t)b) << 16;
    return x.f;
}
__device__ inline uint32_t fbits(float f) {
    union { float f; uint32_t u; } x; x.f = f; return x.u;
}

// Fused canonicalize-to-bf16 for all four inputs. Each block SELF-detects the
// input dtype from x's first 1024 words (bf16 halves ~always "sane", fp32
// mantissa halves ~13% sane) -- removes the serialized 1-block detect kernel.
// The bias block additionally publishes the flag for gemm2's epilogue.
__global__ void convert_all(const void* __restrict__ x,  const void* __restrict__ wq,
                            const void* __restrict__ wp, const void* __restrict__ bias,
                            short* __restrict__ xd, short* __restrict__ wqd,
                            short* __restrict__ wpd, short* __restrict__ biasd,
                            int* __restrict__ flag_out)
{
    __shared__ int cnt;
    if (threadIdx.x == 0) cnt = 0;
    __syncthreads();
    int sane = 0;
    const uint32_t* xu = (const uint32_t*)x;
    for (int i = threadIdx.x; i < 1024; i += 256) {
        float v = bf2f((short)(xu[i] & 0xFFFFu));
        float a = fabsf(v);
        if (a > 1e-5f && a < 1e5f) sane++;
    }
    atomicAdd(&cnt, sane);
    __syncthreads();
    const int isf32 = (cnt < 512) ? 1 : 0;

    const int blk = blockIdx.x;
    const void* src; short* dst; int base, n;
    if (blk < 4096)      { src = x;    dst = xd;    base = blk;        n = B_*T_*C_; }
    else if (blk < 5632) { src = wq;   dst = wqd;   base = blk - 4096; n = 3*C_*C_; }
    else if (blk < 6144) { src = wp;   dst = wpd;   base = blk - 5632; n = C_*C_; }
    else                 { src = bias; dst = biasd; base = 0;          n = C_;
                           if (threadIdx.x == 0) *flag_out = isf32; }
    const int i = (base * 256 + threadIdx.x) * 8;
    if (i >= n) return;
    if (isf32) {
        const float* s = (const float*)src;
        short8 o;
#pragma unroll
        for (int j = 0; j < 8; j++) o[j] = f2bf(s[i + j]);
        *(short8*)&dst[i] = o;
    } else {
        *(short8*)&dst[i] = *(const short8*)((const short*)src + i);
    }
}

// C = A @ B^T (+bias), A[M,K], B[N,K] row-major bf16. (m97 structure, BK=32 —
// BK=64 rejected: async16 forbids padding, 128B rows -> 16-way LDS conflicts.)
template <bool DUAL>
__global__ __launch_bounds__(256) void gemm_bt(
    const short* __restrict__ A, const short* __restrict__ Bm,
    const short* __restrict__ bias_bf, void* __restrict__ Cout,
    int M, int N, int K, const int* __restrict__ flag)
{
    __shared__ short As[128 * 32];
    __shared__ short Bs[128 * 32];
    const int tid  = threadIdx.x;
    const int lane = tid & 63;
    const int wave = tid >> 6;
    const int quad = lane >> 4;
    const int lcol = lane & 15;
    const int m0 = blockIdx.y * 128;
    const int n0 = blockIdx.x * 128;
    const int wm = (wave >> 1) * 64;
    const int wn = (wave & 1) * 64;
    const int isf32 = DUAL ? *flag : 0;

    f32x4 acc[4][4];
#pragma unroll
    for (int i = 0; i < 4; i++)
#pragma unroll
        for (int j = 0; j < 4; j++) acc[i][j] = f32x4{0.f, 0.f, 0.f, 0.f};

    const int idx0 = tid * 8;
    const int row0 = idx0 >> 5, col0 = idx0 & 31;
    const int idx1 = (256 + tid) * 8;
    const int row1 = idx1 >> 5, col1 = idx1 & 31;

    for (int k0 = 0; k0 < K; k0 += 32) {
        async16(&A[(size_t)(m0 + row0) * K + k0 + col0], &As[idx0]);
        async16(&A[(size_t)(m0 + row1) * K + k0 + col1], &As[idx1]);
        async16(&Bm[(size_t)(n0 + row0) * K + k0 + col0], &Bs[idx0]);
        async16(&Bm[(size_t)(n0 + row1) * K + k0 + col1], &Bs[idx1]);
        __syncthreads();

        short8 af[4], bfr[4];
#pragma unroll
        for (int mi = 0; mi < 4; mi++)
            af[mi] = *(const short8*)&As[(wm + mi * 16 + lcol) * 32 + quad * 8];
#pragma unroll
        for (int ni = 0; ni < 4; ni++)
            bfr[ni] = *(const short8*)&Bs[(wn + ni * 16 + lcol) * 32 + quad * 8];
#pragma unroll
        for (int mi = 0; mi < 4; mi++)
#pragma unroll
            for (int ni = 0; ni < 4; ni++)
                acc[mi][ni] = __builtin_amdgcn_mfma_f32_16x16x32_bf16(
                    af[mi], bfr[ni], acc[mi][ni], 0, 0, 0);
        __syncthreads();
    }

#pragma unroll
    for (int ni = 0; ni < 4; ni++) {
        const int col = n0 + wn + ni * 16 + lcol;
        const float bv = bias_bf ? bf2f(bias_bf[col]) : 0.f;
#pragma unroll
        for (int mi = 0; mi < 4; mi++) {
            const int row = m0 + wm + mi * 16 + quad * 4;
#pragma unroll
            for (int r = 0; r < 4; r++) {
                const float val = acc[mi][ni][r] + bv;
                const size_t off = (size_t)(row + r) * N + col;
                if (DUAL && isf32) ((float*)Cout)[off] = val;
                else               ((short*)Cout)[off] = f2bf(val);
            }
        }
    }
}

// Flash attention v9: v8 structure with the paired 128-row chunks split into
// paired 64-row HALF-chunks. Half-chunk (qblk, half) needs 2*qblk+half+1
// key-tiles (sizes enumerate 1..32); pairing (15-i, half=0) with (i, half=1)
// gives a uniform 33 tiles/block. Grid doubles 512->1024 = 4 blocks/CU fully
// co-resident (v8 was grid-capped at 2 blocks/CU -> Occupancy 19%, VALUBusy
// 44%, MfmaUtil 16% = latency-bound). Each wave now carries ONE m-tile's
// state (fewer VGPRs). Cost: each staged K/V tile feeds 16 MFMAs not 32
// (~1.9x staging traffic, L2/L3-served -- acceptable while latency-bound).
// Block mapping pair-major: bh in low 6 bits -> bh%8 selects XCD -> 8 heads'
// K/V (~4MB) per XCD L2.
__global__ __launch_bounds__(256, 4) void attn(const short* __restrict__ qkv,
                                               short* __restrict__ att)
{
    __shared__ short lds_k[64][72];      // K  [key][d], pad 64->72 (stride 36 dw)
    __shared__ short lds_vt[64][68];     // V^T [d][key], pad 64->68 (stride 34 dw)
    __shared__ short lds_p[4][16][76];   // per-wave P [q][key], pad 64->76

    const int tid  = threadIdx.x;
    const int lane = tid & 63;
    const int wave = tid >> 6;
    const int quad = lane >> 4;
    const int lcol = lane & 15;

    const int bh   = blockIdx.x & 63;    // low bits -> XCD locality per head
    const int pi   = blockIdx.x >> 6;    // pair index 0..15
    const int b    = bh >> 4;            // H = 16
    const int h    = bh & 15;

    const size_t rowstride = 3 * C_;     // 3072
    const size_t bhbase = (size_t)b * T_ * rowstride + (size_t)h * (3 * HD_);

    // K staging: 4 lanes per key-row, contiguous 32B each -> b128 LDS writes
    const int kkey = tid >> 2;           // 0..63
    const int kdp  = (tid & 3) * 16;     // 0,16,32,48
    // V staging: one key per lane at fixed 16-d chunk ->
    //    scatter banks = 34*d + key/2 : all 32 banks, 2 lanes each (free)
    const int vkey = tid & 63;
    const int vd0  = (tid >> 6) * 16;    // 0,16,32,48

    short8 kA, kB, vA, vB;
    auto load_tile = [&](int k0) {
        const size_t kb = bhbase + (size_t)(k0 + kkey) * rowstride + HD_ + kdp;
        kA = *(const short8*)&qkv[kb];
        kB = *(const short8*)&qkv[kb + 8];
        const size_t vb = bhbase + (size_t)(k0 + vkey) * rowstride + 2 * HD_ + vd0;
        vA = *(const short8*)&qkv[vb];
        vB = *(const short8*)&qkv[vb + 8];
    };

    const float SC = 0.1803368801f;      // 0.125 * log2(e), folded into Q
    auto scale_frag = [&](short8 q) {
        short8 r;
#pragma unroll
        for (int i = 0; i < 8; i++) r[i] = f2bf(bf2f(q[i]) * SC);
        return r;
    };

    auto process_half = [&](int qblk, int half, bool sync_first) {
        const int q0 = qblk * 128 + half * 64;   // half-chunk base row
        const int qW = q0 + wave * 16;           // this wave's m-tile rows

        // Q fragments (A-operand: m=lcol, k=quad*8+j), pre-scaled
        short8 qf0, qf1;
        {
            const size_t ba = bhbase + (size_t)(qW + lcol) * rowstride + quad * 8;
            qf0 = scale_frag(*(const short8*)&qkv[ba]);
            qf1 = scale_frag(*(const short8*)&qkv[ba + 32]);
        }

        f32x4 o[4];
#pragma unroll
        for (int i = 0; i < 4; i++) o[i] = f32x4{0.f,0.f,0.f,0.f};
        float l[4] = {0.f,0.f,0.f,0.f};

        load_tile(0);

        const int NT = 2 * qblk + half + 1;      // number of key-tiles
        for (int kt = 0; kt < NT; ++kt) {
            if (kt || sync_first) __syncthreads();  // prior LDS reads done
            *(short8*)&lds_k[kkey][kdp]     = kA;
            *(short8*)&lds_k[kkey][kdp + 8] = kB;
#pragma unroll
            for (int jj = 0; jj < 8; jj++) {
                lds_vt[vd0 + jj][vkey]     = vA[jj];
                lds_vt[vd0 + 8 + jj][vkey] = vB[jj];
            }
            __syncthreads();
            if (kt + 1 < NT) load_tile((kt + 1) * 64);  // prefetch overlaps compute

            const int k0 = kt * 64;

            // S fragments
            f32x4 S[4];
#pragma unroll
            for (int t = 0; t < 4; t++) {
                const short8 kf0 = *(const short8*)&lds_k[t * 16 + lcol][quad * 8];
                const short8 kf1 = *(const short8*)&lds_k[t * 16 + lcol][32 + quad * 8];
                S[t] = f32x4{0.f, 0.f, 0.f, 0.f};
                S[t] = __builtin_amdgcn_mfma_f32_16x16x32_bf16(qf0, kf0, S[t], 0, 0, 0);
                S[t] = __builtin_amdgcn_mfma_f32_16x16x32_bf16(qf1, kf1, S[t], 0, 0, 0);
            }

            // V fragments
            short8 vf[4][2];
#pragma unroll
            for (int dt = 0; dt < 4; dt++) {
                vf[dt][0] = *(const short8*)&lds_vt[dt * 16 + lcol][quad * 8];
                vf[dt][1] = *(const short8*)&lds_vt[dt * 16 + lcol][32 + quad * 8];
            }

            const bool mask = (kt == NT - 1);
#pragma unroll
            for (int r = 0; r < 4; r++) {
                const int qrow = qW + quad * 4 + r;
#pragma unroll
                for (int t = 0; t < 4; t++) {
                    float e = __builtin_amdgcn_exp2f(fminf(S[t][r], 88.f));
                    if (mask && (k0 + t * 16 + lcol > qrow)) e = 0.f;
                    l[r] += e;
                    lds_p[wave][quad * 4 + r][t * 16 + lcol] = (short)(fbits(e) >> 16);
                }
            }
            const short8 pf0 = *(const short8*)&lds_p[wave][lcol][quad * 8];
            const short8 pf1 = *(const short8*)&lds_p[wave][lcol][32 + quad * 8];
#pragma unroll
            for (int dt = 0; dt < 4; dt++) {
                o[dt] = __builtin_amdgcn_mfma_f32_16x16x32_bf16(pf0, vf[dt][0], o[dt], 0, 0, 0);
                o[dt] = __builtin_amdgcn_mfma_f32_16x16x32_bf16(pf1, vf[dt][1], o[dt], 0, 0, 0);
            }
        }

        // deferred 16-lane row-sum reductions, normalize + store
#pragma unroll
        for (int r = 0; r < 4; r++) {
            float ra = l[r];
#pragma unroll
            for (int off = 1; off < 16; off <<= 1) ra += __shfl_xor(ra, off);
            const float ia = (ra > 0.f) ? 1.f / ra : 0.f;
            const int qr = qW + quad * 4 + r;
#pragma unroll
            for (int dt = 0; dt < 4; dt++) {
                const int col = h * HD_ + dt * 16 + lcol;
                att[(size_t)(b * T_ + qr) * C_ + col] = f2bf(o[dt][r] * ia);
            }
        }
    };

    process_half(15 - pi, 0, false);   // long half first
    process_half(pi, 1, true);         // complement: total = 33 tiles/block
}

extern "C" void kernel_launch(void* const* d_in, const int* in_sizes, int n_in,
                              void* d_out, int out_size, void* d_ws, size_t ws_size,
                              hipStream_t stream) {
    char* ws = (char*)d_ws;
    short* qkv     = (short*)(ws);                               // 50331648 B
    short* x_or_at = (short*)(ws + 50331648);                    // 16777216 B (x_bf, then att)
    short* wq_bf   = (short*)(ws + 50331648 + 16777216);         //  6291456 B
    short* wp_bf   = (short*)(ws + 50331648 + 16777216 + 6291456);           // 2097152 B
    short* bias_bf = (short*)(ws + 50331648 + 16777216 + 6291456 + 2097152); //    2048 B
    int*   flag    = (int*)  (ws + 50331648 + 16777216 + 6291456 + 2097152 + 2048);

    dim3 blk(256);

    // canonicalize inputs to bf16 (self-detecting dtype); publishes flag
    convert_all<<<dim3(6145), blk, 0, stream>>>(
        d_in[0], d_in[1], d_in[2], d_in[3],
        x_or_at, wq_bf, wp_bf, bias_bf, flag);

    // qkv = x @ W_qkv^T   [8192,3072]
    gemm_bt<false><<<dim3((3 * C_) / 128, (B_ * T_) / 128), blk, 0, stream>>>(
        x_or_at, wq_bf, nullptr, qkv, B_ * T_, 3 * C_, C_, flag);

    // attention -> att (reuses x_bf region; x no longer needed)
    attn<<<dim3(B_ * H_ * (T_ / 128)), blk, 0, stream>>>(qkv, x_or_at);

    // out = att @ W_proj^T + b_proj  (output dtype per flag)
    gemm_bt<true><<<dim3(C_ / 128, (B_ * T_) / 128), blk, 0, stream>>>(
        x_or_at, wp_bf, bias_bf, d_out, B_ * T_, C_, C_, flag);
}